// Round 7
// baseline (183.992 us; speedup 1.0000x reference)
//
#include <hip/hip_runtime.h>
#include <math.h>

// Problem: BS,QLEN,CTX,H,D = 8,1,4096,32,128; START=4095.
// WORLD (established R6): device tensors are FLOAT32 (harness upconverts the
// reference's fp16 since it only supports bf16/f32/int). Output is FLOAT32
// (validator 'else' branch reads raw f32). kvlen = 4096 = CTX -> no masking.
#define BS     8
#define CTX    4096
#define H      32
#define D      128
#define START_IDX 4095
#define NSPLIT 8
#define CHUNK  (CTX / NSPLIT)   // 512
#define THREADS 256
#define NGROUP  16              // 16 key-slots of 16 lanes each
#define SCALE   0.08838834764831843f
#define NEG_BIG (-1.0e30f)

typedef __attribute__((ext_vector_type(8))) float f8;

// Kernel 1: per (b,h) x split, online-softmax partial over CHUNK keys.
// ws layout per (bh,split): [M, L, acc[128]] = 130 floats.
__global__ __launch_bounds__(THREADS, 8)
void attn_partial(const float* __restrict__ xq,
                  const float* __restrict__ xk,
                  const float* __restrict__ xv,
                  const float* __restrict__ cache_k,
                  const float* __restrict__ cache_v,
                  float* __restrict__ ws,
                  float* __restrict__ out,
                  int splits, int write_out)
{
    const int bh    = blockIdx.x;          // 0..255
    const int split = blockIdx.y;
    const int b     = bh >> 5;
    const int h     = bh & 31;
    const int tid   = threadIdx.x;
    const int lane  = tid & 63;
    const int wave  = tid >> 6;
    const int grp   = wave * 4 + (lane >> 4);  // 0..15 key slot
    const int sub   = lane & 15;               // 0..15 column slice
    const int dcol  = sub * 8;                 // 8 f32 = 32B per lane

    f8 qf = *reinterpret_cast<const f8*>(xq + (size_t)bh * D + dcol);

    float m_run = NEG_BIG;
    float l_run = 0.f;
    f8 acc;
    #pragma unroll
    for (int j = 0; j < 8; ++j) acc[j] = 0.f;

    const int chunk = CTX / splits;
    const int k0 = split * chunk;
    const int iters = chunk / NGROUP;

    #pragma unroll 2
    for (int it = 0; it < iters; ++it) {
        const int k = k0 + it * NGROUP + grp;
        const float* kp;
        const float* vp;
        if (k == START_IDX) {               // virtual cache update (new token)
            kp = xk + (size_t)bh * D + dcol;
            vp = xv + (size_t)bh * D + dcol;
        } else {
            size_t off = ((size_t)(b * CTX + k) * H + h) * D + dcol;
            kp = cache_k + off;
            vp = cache_v + off;
        }
        f8 kv = *reinterpret_cast<const f8*>(kp);
        f8 vv = *reinterpret_cast<const f8*>(vp);

        float s = 0.f;
        #pragma unroll
        for (int j = 0; j < 8; ++j) s += kv[j] * qf[j];
        s += __shfl_xor(s, 8);   // masks <16 stay within the 16-lane group
        s += __shfl_xor(s, 4);
        s += __shfl_xor(s, 2);
        s += __shfl_xor(s, 1);
        s *= SCALE;

        // all k in [0, CTX) are valid (kvlen == CTX)
        float m_new = fmaxf(m_run, s);
        float corr  = __expf(m_run - m_new);   // exp(-1e30) == 0 on first hit
        float p     = __expf(s - m_new);
        l_run = l_run * corr + p;
        #pragma unroll
        for (int j = 0; j < 8; ++j)
            acc[j] = acc[j] * corr + p * vv[j];
        m_run = m_new;
    }

    // block-level combine of the 16 group accumulators
    __shared__ float lm[NGROUP];
    __shared__ float ll[NGROUP];
    __shared__ float lacc[NGROUP][D];

    #pragma unroll
    for (int j = 0; j < 8; ++j) lacc[grp][dcol + j] = acc[j];
    if (sub == 0) { lm[grp] = m_run; ll[grp] = l_run; }
    __syncthreads();

    if (tid < D) {
        float M = NEG_BIG;
        #pragma unroll
        for (int g = 0; g < NGROUP; ++g)
            if (ll[g] > 0.f) M = fmaxf(M, lm[g]);
        float L = 0.f, A = 0.f;
        #pragma unroll
        for (int g = 0; g < NGROUP; ++g) {
            if (ll[g] > 0.f) {
                float e = __expf(lm[g] - M);
                L += e * ll[g];
                A += e * lacc[g][tid];
            }
        }
        if (write_out) {
            out[(size_t)bh * D + tid] = (L > 0.f) ? (A / L) : 0.f;
        } else {
            float* part = ws + (size_t)(bh * splits + split) * (D + 2);
            if (tid == 0) { part[0] = M; part[1] = L; }
            part[2 + tid] = A;
        }
    }
}

// Kernel 2: combine NSPLIT partials per (b,h), write f32 output.
__global__ __launch_bounds__(D)
void attn_combine(const float* __restrict__ ws, float* __restrict__ out)
{
    const int bh = blockIdx.x;
    const int d  = threadIdx.x;   // 0..127

    float ms[NSPLIT], ls[NSPLIT];
    float M = NEG_BIG;
    #pragma unroll
    for (int s = 0; s < NSPLIT; ++s) {
        const float* p = ws + (size_t)(bh * NSPLIT + s) * (D + 2);
        ms[s] = p[0];
        ls[s] = p[1];
        if (ls[s] > 0.f) M = fmaxf(M, ms[s]);
    }
    float L = 0.f, A = 0.f;
    #pragma unroll
    for (int s = 0; s < NSPLIT; ++s) {
        if (ls[s] > 0.f) {
            const float* p = ws + (size_t)(bh * NSPLIT + s) * (D + 2);
            float e = __expf(ms[s] - M);
            L += e * ls[s];
            A += e * p[2 + d];
        }
    }
    out[(size_t)bh * D + d] = (L > 0.f) ? (A / L) : 0.f;
}

extern "C" void kernel_launch(void* const* d_in, const int* in_sizes, int n_in,
                              void* d_out, int out_size, void* d_ws, size_t ws_size,
                              hipStream_t stream) {
    // Map inputs by element count (order-robust within same-size classes).
    const int QSZ = BS * H * D;            // 32768
    const int CSZ = BS * CTX * H * D;      // 134217728
    int qi[3] = {0, 1, 2}, ci[2] = {3, 4};
    int nq = 0, nc = 0;
    for (int i = 0; i < n_in; ++i) {
        if (in_sizes[i] == QSZ && nq < 3) qi[nq++] = i;
        else if (in_sizes[i] == CSZ && nc < 2) ci[nc++] = i;
    }
    const float* xq      = (const float*)d_in[qi[0]];
    const float* xk      = (const float*)d_in[qi[1]];
    const float* xv      = (const float*)d_in[qi[2]];
    const float* cache_k = (const float*)d_in[ci[0]];
    const float* cache_v = (const float*)d_in[ci[1]];
    float* ws  = (float*)d_ws;
    float* out = (float*)d_out;

    const size_t ws_needed = (size_t)(BS * H) * NSPLIT * (D + 2) * sizeof(float);
    if (ws != nullptr && ws_size >= ws_needed) {
        dim3 grid1(BS * H, NSPLIT);
        attn_partial<<<grid1, THREADS, 0, stream>>>(
            xq, xk, xv, cache_k, cache_v, ws, out, NSPLIT, 0);
        attn_combine<<<BS * H, D, 0, stream>>>(ws, out);
    } else {
        dim3 grid1(BS * H, 1);
        attn_partial<<<grid1, THREADS, 0, stream>>>(
            xq, xk, xv, cache_k, cache_v, nullptr, out, 1, 1);
    }
}